// Round 11
// baseline (202.380 us; speedup 1.0000x reference)
//
#include <hip/hip_runtime.h>
#include <math.h>

// (B, T, D, H, L) = (8, 512, 128, 128, 2). All fp32 I/O.
#define BB 8
#define TT 512
#define DD 128
#define HH 128
#define BT_ (BB * TT)                 // 4096
#define CL 32                         // C-scan chunk length
#define NCH 16                        // number of chunks (TT/CL)
static const size_t BTH = (size_t)BT_ * HH;  // 524288

// ws layout: act planes [0,6*BTH) : q | k | ifpack(2*BTH) | vopack(2*BTH)
//   q:      act + 0      [row][h]
//   k:      act + BTH    [row][h]     (pre-scaled by 1/sqrt(H) in proj)
//   ifpack: act + 2*BTH  [row][2h+{0:i,1:f}]
//   vopack: act + 4*BTH  [row][2h+{0:v,1:o}]  (o scaled in-LDS in hscan3)
// hbuf = act + 6*BTH (layer-1 output).
// cbuf  = act + 7*BTH: C-chunk summaries [(b*128+p)*NCH+ch][128] (8 MB);
//         ccomb2 converts IN PLACE to chunk-START C's (exclusive prefix).
// abuf  = cbuf + 1024*NCH*128: chunk A=prod f, layout [ch][b][p]   (16K)
// segA8 = abuf + 16384:  8-step n-A, layout [(b*128+p)*64 + seg]   (64K)
// segB8 = segA8 + 65536: 8-step n-B, same layout                   (64K)
// nstart= segB8 + 65536: n at START of seg, layout [seg][b][p]     (64K)
// d_out: Wt [0,196608) transposed weights; consumed by both proj dispatches,
// then overwritten by the final hscan3 output (stream-ordered, safe).

struct WArgs { const float* W[6]; };
struct BArgs { const float* b[6]; };

template <int CTRL>
__device__ __forceinline__ float dpp_add(float x) {
  int y = __builtin_amdgcn_update_dpp(0, __builtin_bit_cast(int, x), CTRL,
                                      0xF, 0xF, true);
  return x + __builtin_bit_cast(float, y);
}

// DPP move with identity fill: invalid lanes keep `old` (bound_ctrl=false).
template <int CTRL>
__device__ __forceinline__ float dpp_mov(float old, float x) {
  int y = __builtin_amdgcn_update_dpp(__builtin_bit_cast(int, old),
                                      __builtin_bit_cast(int, x), CTRL,
                                      0xF, 0xF, false);
  return __builtin_bit_cast(float, y);
}

// ---------------------------------------------------------------------------
// Transpose all 12 weight slabs: Wt[l*6+p][d][h] = W_p[l][h][d].
// ---------------------------------------------------------------------------
__global__ __launch_bounds__(256)
void transpose_w(WArgs w, float* __restrict__ Wt) {
  __shared__ float t[32][33];
  const int l = blockIdx.y / 6, p = blockIdx.y % 6;
  const float* src = w.W[p] + (size_t)l * HH * DD;
  float* dst = Wt + (size_t)blockIdx.y * HH * DD;
  const int ty0 = (blockIdx.x >> 2) * 32, tx0 = (blockIdx.x & 3) * 32;
  const int tx = threadIdx.x & 31, ty = threadIdx.x >> 5;
#pragma unroll
  for (int j = 0; j < 32; j += 8)
    t[ty + j][tx] = src[(size_t)(ty0 + ty + j) * DD + tx0 + tx];
  __syncthreads();
#pragma unroll
  for (int j = 0; j < 32; j += 8)
    dst[(size_t)(tx0 + ty + j) * HH + ty0 + tx] = t[tx][ty + j];
}

// ---------------------------------------------------------------------------
// Projection v2 (proven round 9): grid (BT_/64, 6), block 256.
// Thread = 4 rows x 8 h (64-row x 128-h tile).
// ---------------------------------------------------------------------------
__global__ __launch_bounds__(256)
void proj_kernel(const float* __restrict__ X, const float* __restrict__ Wtl,
                 BArgs args, float* __restrict__ act) {
  __shared__ float xs[64][132];
  const int p = blockIdx.y;
  const int row0 = blockIdx.x * 64;
  const int tid = threadIdx.x;
  {
    const float4* xg = (const float4*)(X + (size_t)row0 * DD);
#pragma unroll
    for (int i = 0; i < 8; ++i) {
      int u = tid + 256 * i;  // float4 index within 64x128 tile
      float4 v = xg[u];
      *(float4*)&xs[u >> 5][(u & 31) * 4] = v;
    }
  }
  __syncthreads();

  const int h0 = (tid & 15) * 8;
  const int r0 = (tid >> 4) * 4;
  const float* wtp = Wtl + (size_t)p * HH * DD;

  float acc[4][8];
#pragma unroll
  for (int r = 0; r < 4; ++r)
#pragma unroll
    for (int j = 0; j < 8; ++j) acc[r][j] = 0.f;

  for (int d0 = 0; d0 < DD; d0 += 4) {
    float4 wa[4], wb[4];
#pragma unroll
    for (int i = 0; i < 4; ++i) {
      wa[i] = *(const float4*)(wtp + (size_t)(d0 + i) * HH + h0);
      wb[i] = *(const float4*)(wtp + (size_t)(d0 + i) * HH + h0 + 4);
    }
    float4 xr[4];
#pragma unroll
    for (int r = 0; r < 4; ++r) xr[r] = *(const float4*)&xs[r0 + r][d0];
#pragma unroll
    for (int i = 0; i < 4; ++i) {
#pragma unroll
      for (int r = 0; r < 4; ++r) {
        const float xv = (i == 0) ? xr[r].x
                        : (i == 1) ? xr[r].y
                        : (i == 2) ? xr[r].z : xr[r].w;
        acc[r][0] = fmaf(xv, wa[i].x, acc[r][0]);
        acc[r][1] = fmaf(xv, wa[i].y, acc[r][1]);
        acc[r][2] = fmaf(xv, wa[i].z, acc[r][2]);
        acc[r][3] = fmaf(xv, wa[i].w, acc[r][3]);
        acc[r][4] = fmaf(xv, wb[i].x, acc[r][4]);
        acc[r][5] = fmaf(xv, wb[i].y, acc[r][5]);
        acc[r][6] = fmaf(xv, wb[i].z, acc[r][6]);
        acc[r][7] = fmaf(xv, wb[i].w, acc[r][7]);
      }
    }
  }

  const float4 b0 = *(const float4*)(args.b[p] + h0);
  const float4 b1 = *(const float4*)(args.b[p] + h0 + 4);
  const float bias[8] = {b0.x, b0.y, b0.z, b0.w, b1.x, b1.y, b1.z, b1.w};
#pragma unroll
  for (int r = 0; r < 4; ++r) {
    const size_t row = (size_t)row0 + r0 + r;
    float v[8];
#pragma unroll
    for (int j = 0; j < 8; ++j) {
      float a = acc[r][j] + bias[j];
      if (p == 1)      a *= 0.088388347648318447f;   // 1/sqrt(128)
      else if (p == 3) a = __expf(a);
      else if (p >= 4) a = 1.0f / (1.0f + __expf(-a));
      v[j] = a;
    }
    if (p == 0) {
      float* dst = act + row * HH + h0;
      *(float4*)dst = make_float4(v[0], v[1], v[2], v[3]);
      *(float4*)(dst + 4) = make_float4(v[4], v[5], v[6], v[7]);
    } else if (p == 1) {
      float* dst = act + BTH + row * HH + h0;
      *(float4*)dst = make_float4(v[0], v[1], v[2], v[3]);
      *(float4*)(dst + 4) = make_float4(v[4], v[5], v[6], v[7]);
    } else if (p == 3 || p == 4) {       // i -> slot 0, f -> slot 1
      float* dst = act + 2 * BTH + row * 2 * HH + 2 * h0 + (p == 3 ? 0 : 1);
#pragma unroll
      for (int j = 0; j < 8; ++j) dst[2 * j] = v[j];
    } else {                             // v -> slot 0, o -> slot 1
      float* dst = act + 4 * BTH + row * 2 * HH + 2 * h0 + (p == 2 ? 0 : 1);
#pragma unroll
      for (int j = 0; j < 8; ++j) dst[2 * j] = v[j];
    }
  }
}

// ---------------------------------------------------------------------------
// cseg2: block-tiled chunk summaries (proven round 7) + 8-step n-summaries
// (chain-major layout for ccomb2's coalesced wave-scan read).
// grid 512 (b, ch, qtr), block 512.
// ---------------------------------------------------------------------------
__global__ __launch_bounds__(512)
void cseg2_kernel(const float* __restrict__ act, float* __restrict__ cbuf,
                  float* __restrict__ abuf, float* __restrict__ segA8,
                  float* __restrict__ segB8) {
  __shared__ __align__(16) float kt[CL][128];
  __shared__ __align__(16) float ift[CL][64];
  __shared__ __align__(16) float vot[CL][64];
  const int tid = threadIdx.x;
  const int lane = tid & 63, wid = tid >> 6;
  const int blk = blockIdx.x;
  const int b = blk & 7, ch = (blk >> 3) & (NCH - 1), qtr = blk >> 7;
  const int t0 = ch * CL;
  const int p0 = qtr * 32;
  const size_t boff = (size_t)b * TT * HH;
  const float* kg = act + BTH + boff;
  const float* ifg = act + 2 * BTH + 2 * boff;
  const float* vog = act + 4 * BTH + 2 * boff;

#pragma unroll
  for (int i = 0; i < CL / 16; ++i) {
    const int u = tid + 512 * i;                 // f4 index
    const int r = u >> 5, c = (u & 31) * 4;
    *(float4*)&kt[r][c] = *(const float4*)(kg + (size_t)(t0 + r) * HH + c);
  }
  {
    const int r = tid >> 4, c = (tid & 15) * 4;  // 512 f4 = CL x 64
    *(float4*)&ift[r][c] =
        *(const float4*)(ifg + (size_t)(t0 + r) * 2 * HH + 2 * p0 + c);
    *(float4*)&vot[r][c] =
        *(const float4*)(vog + (size_t)(t0 + r) * 2 * HH + 2 * p0 + c);
  }
  __syncthreads();

  const int pl = lane >> 4, cl = lane & 15;
  const int plocal = wid * 4 + pl;               // 0..31
  const int p = p0 + plocal;

  float C[8];
#pragma unroll
  for (int j = 0; j < 8; ++j) C[j] = 0.f;
  float Af = 1.f, Aw = 1.f, Bw = 0.f;

#pragma unroll 4
  for (int t = 0; t < CL; ++t) {
    const float2 gif = *(const float2*)&ift[t][2 * plocal];
    const float2 gvo = *(const float2*)&vot[t][2 * plocal];
    const float4 k0 = *(const float4*)&kt[t][cl * 4];
    const float4 k1 = *(const float4*)&kt[t][cl * 4 + 64];
    const float kp = kt[t][p];                   // broadcast across cl lanes
    const float a = gif.x * gvo.x;               // i*v
    const float f = gif.y;
    C[0] = fmaf(f, C[0], a * k0.x);
    C[1] = fmaf(f, C[1], a * k0.y);
    C[2] = fmaf(f, C[2], a * k0.z);
    C[3] = fmaf(f, C[3], a * k0.w);
    C[4] = fmaf(f, C[4], a * k1.x);
    C[5] = fmaf(f, C[5], a * k1.y);
    C[6] = fmaf(f, C[6], a * k1.z);
    C[7] = fmaf(f, C[7], a * k1.w);
    Af *= f;
    Aw *= f;
    Bw = fmaf(f, Bw, gif.x * kp);                // 8-step n-summary
    if ((t & 7) == 7) {
      if (cl == 0) {
        const size_t si = (size_t)(b * 128 + p) * 64 + ch * 4 + (t >> 3);
        segA8[si] = Aw;
        segB8[si] = Bw;
      }
      Aw = 1.f;
      Bw = 0.f;
    }
  }

  const size_t slot = (size_t)(b * 128 + p) * NCH + ch;
  *(float4*)(cbuf + slot * 128 + cl * 4) = make_float4(C[0], C[1], C[2], C[3]);
  *(float4*)(cbuf + slot * 128 + cl * 4 + 64) =
      make_float4(C[4], C[5], C[6], C[7]);
  if (cl == 0) abuf[(size_t)ch * 1024 + b * 128 + p] = Af;
}

// ---------------------------------------------------------------------------
// ccomb2: per chain (b*128+p), 128 threads.
// Phase 1 (all threads, thread = col c): exclusive prefix of the 16 C-chunk
//   summaries IN PLACE -> slot ch holds C at START of chunk ch.
// Phase 2 (wave 0, lane = seg): proven DPP affine wave-scan (round-2 nsum)
//   over the 64 8-step n-summaries -> nstart[seg][b][p] (exclusive; seg0=0).
// ---------------------------------------------------------------------------
__global__ __launch_bounds__(128)
void ccomb2_kernel(float* __restrict__ cbuf, const float* __restrict__ abuf,
                   const float* __restrict__ segA8,
                   const float* __restrict__ segB8,
                   float* __restrict__ nstart) {
  const int chain = blockIdx.x;        // b*128 + p
  const int c = threadIdx.x;
  float A[NCH], Bv[NCH];
#pragma unroll
  for (int g = 0; g < NCH; ++g) {
    A[g] = abuf[(size_t)g * 1024 + chain];
    Bv[g] = cbuf[((size_t)chain * NCH + g) * 128 + c];
  }
  float Cs = 0.f;
#pragma unroll
  for (int g = 0; g < NCH; ++g) {
    cbuf[((size_t)chain * NCH + g) * 128 + c] = Cs;
    Cs = fmaf(A[g], Cs, Bv[g]);
  }
  if (c < 64) {
    const int lane = c;                // seg index
    float a = segA8[(size_t)chain * 64 + lane];
    float bn = segB8[(size_t)chain * 64 + lane];
#define SCAN_LVL(CTRL)                          \
  {                                             \
    float As = dpp_mov<CTRL>(1.0f, a);          \
    float Bs = dpp_mov<CTRL>(0.0f, bn);         \
    bn = fmaf(a, Bs, bn);                       \
    a = a * As;                                 \
  }
    SCAN_LVL(0x111)  // row_shr:1
    SCAN_LVL(0x112)  // row_shr:2
    SCAN_LVL(0x114)  // row_shr:4
    SCAN_LVL(0x118)  // row_shr:8
    SCAN_LVL(0x142)  // row_bcast:15
    SCAN_LVL(0x143)  // row_bcast:31
#undef SCAN_LVL
    const int idx = (lane + 1) & 63;
    nstart[(size_t)idx * 1024 + chain] = (lane == 63) ? 0.f : bn;
  }
}

// ---------------------------------------------------------------------------
// hscan3 v2: den + replay fused, now with O(1) composes. grid 512 (b, ch,
// qtr), block 512. Stages q/k (full 128h) + i,f (ALL 128 p) + v,o (own qtr).
// Den phase: thread (seg = tid>>7, pd = tid&127): n-start = ONE coalesced
// load from nstart; 8 local steps from LDS; proven 6-step DPP reduce +
// cross-wave combine; o scaled in LDS. Replay: start-C = ONE cbuf slot
// (prefix-composed by ccomb2); round-7 replay verbatim. LDS 72.4 KB.
// ---------------------------------------------------------------------------
__global__ __launch_bounds__(512)
void hscan3_kernel(const float* __restrict__ act, float* __restrict__ hout,
                   const float* __restrict__ cbuf,
                   const float* __restrict__ nstart) {
  __shared__ __align__(16) float qt[CL][128];    // 16 KB
  __shared__ __align__(16) float kt[CL][128];    // 16 KB
  __shared__ __align__(16) float iff[CL][256];   // 32 KB (i,f all 128 p)
  __shared__ __align__(16) float vot[CL][64];    // 8 KB (v,o own qtr)
  __shared__ float den_part[4][8][2];
  __shared__ float den[CL];
  const int tid = threadIdx.x;
  const int lane = tid & 63, wid = tid >> 6;
  const int blk = blockIdx.x;
  const int b = blk & 7, ch = (blk >> 3) & (NCH - 1), qtr = blk >> 7;
  const int t0 = ch * CL;
  const int p0 = qtr * 32;
  const size_t boff = (size_t)b * TT * HH;
  const float* qg = act + boff;
  const float* kg = act + BTH + boff;
  const float* ifg = act + 2 * BTH + 2 * boff;
  const float* vog = act + 4 * BTH + 2 * boff;

#pragma unroll
  for (int i = 0; i < CL / 16; ++i) {
    const int u = tid + 512 * i;
    const int r = u >> 5, c = (u & 31) * 4;
    *(float4*)&qt[r][c] = *(const float4*)(qg + (size_t)(t0 + r) * HH + c);
    *(float4*)&kt[r][c] = *(const float4*)(kg + (size_t)(t0 + r) * HH + c);
  }
#pragma unroll
  for (int i = 0; i < 4; ++i) {                  // CL x 256 = 2048 f4
    const int u = tid + 512 * i;
    const int r = u >> 6, c = (u & 63) * 4;
    *(float4*)&iff[r][c] =
        *(const float4*)(ifg + (size_t)(t0 + r) * 2 * HH + c);
  }
  {
    const int r = tid >> 4, c = (tid & 15) * 4;
    *(float4*)&vot[r][c] =
        *(const float4*)(vog + (size_t)(t0 + r) * 2 * HH + 2 * p0 + c);
  }
  __syncthreads();

  // ---- den phase: thread = (seg, pd); n-start is one coalesced load ----
  {
    const int seg = tid >> 7, pd = tid & 127;
    float n = nstart[(size_t)(ch * 4 + seg) * 1024 + b * 128 + pd];
    float prod[8];
#pragma unroll
    for (int j = 0; j < 8; ++j) {
      const int tl = seg * 8 + j;
      const float iv = iff[tl][2 * pd];
      const float fv = iff[tl][2 * pd + 1];
      prod[j] = n * qt[tl][pd];                  // OLD n (n_{t-1})
      n = fmaf(fv, n, iv * kt[tl][pd]);
    }
#pragma unroll
    for (int j = 0; j < 8; ++j) {
      float s = prod[j];
      s = dpp_add<0x111>(s);
      s = dpp_add<0x112>(s);
      s = dpp_add<0x114>(s);
      s = dpp_add<0x118>(s);
      s = dpp_add<0x142>(s);
      s = dpp_add<0x143>(s);
      prod[j] = s;
    }
    if (lane == 63) {
#pragma unroll
      for (int j = 0; j < 8; ++j) den_part[seg][j][wid & 1] = prod[j];
    }
  }
  __syncthreads();
  if (tid < CL) {
    const int s_ = tid >> 3, j_ = tid & 7;
    const float d = den_part[s_][j_][0] + den_part[s_][j_][1];
    den[tid] = __builtin_amdgcn_rcpf(fmaxf(fabsf(d), 1.0f));
  }
  __syncthreads();
  {
    int u = tid;                                 // 32 t x 32 pp o-elements
    vot[u >> 5][2 * (u & 31) + 1] *= den[u >> 5];
    u = tid + 512;
    vot[u >> 5][2 * (u & 31) + 1] *= den[u >> 5];
  }
  __syncthreads();

  // ---- replay (round-7 hscan2); start-C = one prefix-composed slot ----
  const int pl = lane >> 4, cl = lane & 15;
  const int plocal = wid * 4 + pl;
  const int p = p0 + plocal;

  float C[8];
  {
    const size_t slot = ((size_t)(b * 128 + p) * NCH + ch) * 128;
    const float4 c0 = *(const float4*)(cbuf + slot + cl * 4);
    const float4 c1 = *(const float4*)(cbuf + slot + cl * 4 + 64);
    C[0] = c0.x; C[1] = c0.y; C[2] = c0.z; C[3] = c0.w;
    C[4] = c1.x; C[5] = c1.y; C[6] = c1.z; C[7] = c1.w;
  }
  float* hbase = hout + boff + p;

#pragma unroll 4
  for (int t = 0; t < CL; ++t) {
    const float2 gif = *(const float2*)&iff[t][2 * p];
    const float2 gvo = *(const float2*)&vot[t][2 * plocal];
    const float4 q0 = *(const float4*)&qt[t][cl * 4];
    const float4 q1 = *(const float4*)&qt[t][cl * 4 + 64];
    const float4 k0 = *(const float4*)&kt[t][cl * 4];
    const float4 k1 = *(const float4*)&kt[t][cl * 4 + 64];
    // h-tilde partial from OLD C
    float s0 = C[0] * q0.x;
    float s1 = C[4] * q1.x;
    s0 = fmaf(C[1], q0.y, s0);
    s1 = fmaf(C[5], q1.y, s1);
    s0 = fmaf(C[2], q0.z, s0);
    s1 = fmaf(C[6], q1.z, s1);
    s0 = fmaf(C[3], q0.w, s0);
    s1 = fmaf(C[7], q1.w, s1);
    float s = s0 + s1;
    // C update
    const float a = gif.x * gvo.x;               // i*v
    const float f = gif.y;
    C[0] = fmaf(f, C[0], a * k0.x);
    C[1] = fmaf(f, C[1], a * k0.y);
    C[2] = fmaf(f, C[2], a * k0.z);
    C[3] = fmaf(f, C[3], a * k0.w);
    C[4] = fmaf(f, C[4], a * k1.x);
    C[5] = fmaf(f, C[5], a * k1.y);
    C[6] = fmaf(f, C[6], a * k1.z);
    C[7] = fmaf(f, C[7], a * k1.w);
    // reduce over the 16-lane row: lane cl==15 holds the full col-sum
    s = dpp_add<0x111>(s);
    s = dpp_add<0x112>(s);
    s = dpp_add<0x114>(s);
    s = dpp_add<0x118>(s);
    if (cl == 15) hbase[(size_t)(t0 + t) * HH] = s * gvo.y;  // o*invden
  }
}

// ---------------------------------------------------------------------------
extern "C" void kernel_launch(void* const* d_in, const int* in_sizes, int n_in,
                              void* d_out, int out_size, void* d_ws,
                              size_t ws_size, hipStream_t stream) {
  (void)in_sizes; (void)n_in; (void)out_size; (void)ws_size;
  const float* x = (const float*)d_in[0];
  float* act = (float*)d_ws;                     // 6 * BTH floats
  float* hbuf = act + 6 * BTH;                   // BTH floats (layer-1 h)
  float* cbuf = act + 7 * BTH;                   // 1024*NCH*128 floats (8 MB)
  float* abuf = cbuf + (size_t)1024 * NCH * 128; // 16K floats
  float* segA8 = abuf + 16384;                   // 64K floats
  float* segB8 = segA8 + 65536;                  // 64K floats
  float* nstart = segB8 + 65536;                 // 64K floats
  float* Wt = (float*)d_out;                     // [0, 196608)

  WArgs wa;
  for (int j = 0; j < 6; ++j) wa.W[j] = (const float*)d_in[1 + j];
  transpose_w<<<dim3(16, 12), 256, 0, stream>>>(wa, Wt);

  for (int l = 0; l < 2; ++l) {
    BArgs ba;
    for (int j = 0; j < 6; ++j)
      ba.b[j] = (const float*)d_in[7 + j] + (size_t)l * HH;
    const float* wtl = Wt + (size_t)l * 6 * HH * DD;
    const float* xin = (l == 0) ? x : hbuf;
    float* hdst = (l == 0) ? hbuf : (float*)d_out;
    proj_kernel<<<dim3(BT_ / 64, 6), 256, 0, stream>>>(xin, wtl, ba, act);
    cseg2_kernel<<<512, 512, 0, stream>>>(act, cbuf, abuf, segA8, segB8);
    ccomb2_kernel<<<1024, 128, 0, stream>>>(cbuf, abuf, segA8, segB8, nstart);
    hscan3_kernel<<<512, 512, 0, stream>>>(act, hdst, cbuf, nstart);
  }
}

// Round 12
// 198.101 us; speedup vs baseline: 1.0216x; 1.0216x over previous
//
#include <hip/hip_runtime.h>
#include <math.h>

// (B, T, D, H, L) = (8, 512, 128, 128, 2). All fp32 I/O.
#define BB 8
#define TT 512
#define DD 128
#define HH 128
#define BT_ (BB * TT)                 // 4096
#define CL 32                         // C-scan chunk length
#define NCH 16                        // number of chunks (TT/CL)
static const size_t BTH = (size_t)BT_ * HH;  // 524288

// ws layout: act planes [0,6*BTH) : q | k | ifpack(2*BTH) | vopack(2*BTH)
//   q:      act + 0      [row][h]
//   k:      act + BTH    [row][h]     (pre-scaled by 1/sqrt(H) in proj)
//   ifpack: act + 2*BTH  [row][2h+{0:i,1:f}]
//   vopack: act + 4*BTH  [row][2h+{0:v,1:o}]  (o scaled in-LDS in hscan3)
// hbuf = act + 6*BTH (layer-1 output).
// cbuf  = act + 7*BTH: C-chunk summaries [(b*128+p)*NCH+ch][128]  (8 MB)
// abuf  = cbuf + 1024*NCH*128: chunk A=prod f,  layout [ch][b][p] (16K)
// nbufB = abuf + 16384:        chunk n-B,       layout [ch][b][p] (16K)
// segA8 = nbufB + 16384:       8-step n-A, [ch*4+s][b][p]         (64K)
// segB8 = segA8 + 65536:       8-step n-B, [ch*4+s][b][p]         (64K)
// d_out: Wt [0,196608) transposed weights; consumed by both proj dispatches,
// then overwritten by the final hscan3 output (stream-ordered, safe).

struct WArgs { const float* W[6]; };
struct BArgs { const float* b[6]; };

template <int CTRL>
__device__ __forceinline__ float dpp_add(float x) {
  int y = __builtin_amdgcn_update_dpp(0, __builtin_bit_cast(int, x), CTRL,
                                      0xF, 0xF, true);
  return x + __builtin_bit_cast(float, y);
}

// ---------------------------------------------------------------------------
// Transpose all 12 weight slabs: Wt[l*6+p][d][h] = W_p[l][h][d].
// ---------------------------------------------------------------------------
__global__ __launch_bounds__(256)
void transpose_w(WArgs w, float* __restrict__ Wt) {
  __shared__ float t[32][33];
  const int l = blockIdx.y / 6, p = blockIdx.y % 6;
  const float* src = w.W[p] + (size_t)l * HH * DD;
  float* dst = Wt + (size_t)blockIdx.y * HH * DD;
  const int ty0 = (blockIdx.x >> 2) * 32, tx0 = (blockIdx.x & 3) * 32;
  const int tx = threadIdx.x & 31, ty = threadIdx.x >> 5;
#pragma unroll
  for (int j = 0; j < 32; j += 8)
    t[ty + j][tx] = src[(size_t)(ty0 + ty + j) * DD + tx0 + tx];
  __syncthreads();
#pragma unroll
  for (int j = 0; j < 32; j += 8)
    dst[(size_t)(tx0 + ty + j) * HH + ty0 + tx] = t[tx][ty + j];
}

// ---------------------------------------------------------------------------
// Projection v2 (proven round 9): grid (BT_/64, 6), block 256.
// Thread = 4 rows x 8 h (64-row x 128-h tile).
// ---------------------------------------------------------------------------
__global__ __launch_bounds__(256)
void proj_kernel(const float* __restrict__ X, const float* __restrict__ Wtl,
                 BArgs args, float* __restrict__ act) {
  __shared__ float xs[64][132];
  const int p = blockIdx.y;
  const int row0 = blockIdx.x * 64;
  const int tid = threadIdx.x;
  {
    const float4* xg = (const float4*)(X + (size_t)row0 * DD);
#pragma unroll
    for (int i = 0; i < 8; ++i) {
      int u = tid + 256 * i;  // float4 index within 64x128 tile
      float4 v = xg[u];
      *(float4*)&xs[u >> 5][(u & 31) * 4] = v;
    }
  }
  __syncthreads();

  const int h0 = (tid & 15) * 8;
  const int r0 = (tid >> 4) * 4;
  const float* wtp = Wtl + (size_t)p * HH * DD;

  float acc[4][8];
#pragma unroll
  for (int r = 0; r < 4; ++r)
#pragma unroll
    for (int j = 0; j < 8; ++j) acc[r][j] = 0.f;

  for (int d0 = 0; d0 < DD; d0 += 4) {
    float4 wa[4], wb[4];
#pragma unroll
    for (int i = 0; i < 4; ++i) {
      wa[i] = *(const float4*)(wtp + (size_t)(d0 + i) * HH + h0);
      wb[i] = *(const float4*)(wtp + (size_t)(d0 + i) * HH + h0 + 4);
    }
    float4 xr[4];
#pragma unroll
    for (int r = 0; r < 4; ++r) xr[r] = *(const float4*)&xs[r0 + r][d0];
#pragma unroll
    for (int i = 0; i < 4; ++i) {
#pragma unroll
      for (int r = 0; r < 4; ++r) {
        const float xv = (i == 0) ? xr[r].x
                        : (i == 1) ? xr[r].y
                        : (i == 2) ? xr[r].z : xr[r].w;
        acc[r][0] = fmaf(xv, wa[i].x, acc[r][0]);
        acc[r][1] = fmaf(xv, wa[i].y, acc[r][1]);
        acc[r][2] = fmaf(xv, wa[i].z, acc[r][2]);
        acc[r][3] = fmaf(xv, wa[i].w, acc[r][3]);
        acc[r][4] = fmaf(xv, wb[i].x, acc[r][4]);
        acc[r][5] = fmaf(xv, wb[i].y, acc[r][5]);
        acc[r][6] = fmaf(xv, wb[i].z, acc[r][6]);
        acc[r][7] = fmaf(xv, wb[i].w, acc[r][7]);
      }
    }
  }

  const float4 b0 = *(const float4*)(args.b[p] + h0);
  const float4 b1 = *(const float4*)(args.b[p] + h0 + 4);
  const float bias[8] = {b0.x, b0.y, b0.z, b0.w, b1.x, b1.y, b1.z, b1.w};
#pragma unroll
  for (int r = 0; r < 4; ++r) {
    const size_t row = (size_t)row0 + r0 + r;
    float v[8];
#pragma unroll
    for (int j = 0; j < 8; ++j) {
      float a = acc[r][j] + bias[j];
      if (p == 1)      a *= 0.088388347648318447f;   // 1/sqrt(128)
      else if (p == 3) a = __expf(a);
      else if (p >= 4) a = 1.0f / (1.0f + __expf(-a));
      v[j] = a;
    }
    if (p == 0) {
      float* dst = act + row * HH + h0;
      *(float4*)dst = make_float4(v[0], v[1], v[2], v[3]);
      *(float4*)(dst + 4) = make_float4(v[4], v[5], v[6], v[7]);
    } else if (p == 1) {
      float* dst = act + BTH + row * HH + h0;
      *(float4*)dst = make_float4(v[0], v[1], v[2], v[3]);
      *(float4*)(dst + 4) = make_float4(v[4], v[5], v[6], v[7]);
    } else if (p == 3 || p == 4) {       // i -> slot 0, f -> slot 1
      float* dst = act + 2 * BTH + row * 2 * HH + 2 * h0 + (p == 3 ? 0 : 1);
#pragma unroll
      for (int j = 0; j < 8; ++j) dst[2 * j] = v[j];
    } else {                             // v -> slot 0, o -> slot 1
      float* dst = act + 4 * BTH + row * 2 * HH + 2 * h0 + (p == 2 ? 0 : 1);
#pragma unroll
      for (int j = 0; j < 8; ++j) dst[2 * j] = v[j];
    }
  }
}

// ---------------------------------------------------------------------------
// cseg2: block-tiled chunk summaries (proven round 7) + 8-step n-summaries
// (proven round 8 phase A). grid 512 (b, ch, qtr), block 512.
// ---------------------------------------------------------------------------
__global__ __launch_bounds__(512)
void cseg2_kernel(const float* __restrict__ act, float* __restrict__ cbuf,
                  float* __restrict__ abuf, float* __restrict__ nbufB,
                  float* __restrict__ segA8, float* __restrict__ segB8) {
  __shared__ __align__(16) float kt[CL][128];
  __shared__ __align__(16) float ift[CL][64];
  __shared__ __align__(16) float vot[CL][64];
  const int tid = threadIdx.x;
  const int lane = tid & 63, wid = tid >> 6;
  const int blk = blockIdx.x;
  const int b = blk & 7, ch = (blk >> 3) & (NCH - 1), qtr = blk >> 7;
  const int t0 = ch * CL;
  const int p0 = qtr * 32;
  const size_t boff = (size_t)b * TT * HH;
  const float* kg = act + BTH + boff;
  const float* ifg = act + 2 * BTH + 2 * boff;
  const float* vog = act + 4 * BTH + 2 * boff;

#pragma unroll
  for (int i = 0; i < CL / 16; ++i) {
    const int u = tid + 512 * i;                 // f4 index
    const int r = u >> 5, c = (u & 31) * 4;
    *(float4*)&kt[r][c] = *(const float4*)(kg + (size_t)(t0 + r) * HH + c);
  }
  {
    const int r = tid >> 4, c = (tid & 15) * 4;  // 512 f4 = CL x 64
    *(float4*)&ift[r][c] =
        *(const float4*)(ifg + (size_t)(t0 + r) * 2 * HH + 2 * p0 + c);
    *(float4*)&vot[r][c] =
        *(const float4*)(vog + (size_t)(t0 + r) * 2 * HH + 2 * p0 + c);
  }
  __syncthreads();

  const int pl = lane >> 4, cl = lane & 15;
  const int plocal = wid * 4 + pl;               // 0..31
  const int p = p0 + plocal;

  float C[8];
#pragma unroll
  for (int j = 0; j < 8; ++j) C[j] = 0.f;
  float Af = 1.f, Bn = 0.f, Aw = 1.f, Bw = 0.f;

#pragma unroll 4
  for (int t = 0; t < CL; ++t) {
    const float2 gif = *(const float2*)&ift[t][2 * plocal];
    const float2 gvo = *(const float2*)&vot[t][2 * plocal];
    const float4 k0 = *(const float4*)&kt[t][cl * 4];
    const float4 k1 = *(const float4*)&kt[t][cl * 4 + 64];
    const float kp = kt[t][p];                   // broadcast across cl lanes
    const float a = gif.x * gvo.x;               // i*v
    const float f = gif.y;
    C[0] = fmaf(f, C[0], a * k0.x);
    C[1] = fmaf(f, C[1], a * k0.y);
    C[2] = fmaf(f, C[2], a * k0.z);
    C[3] = fmaf(f, C[3], a * k0.w);
    C[4] = fmaf(f, C[4], a * k1.x);
    C[5] = fmaf(f, C[5], a * k1.y);
    C[6] = fmaf(f, C[6], a * k1.z);
    C[7] = fmaf(f, C[7], a * k1.w);
    Af *= f;
    Bn = fmaf(f, Bn, gif.x * kp);                // chunk n-summary
    Aw *= f;
    Bw = fmaf(f, Bw, gif.x * kp);                // 8-step n-summary
    if ((t & 7) == 7) {
      if (cl == 0) {
        const size_t si = (size_t)(ch * 4 + (t >> 3)) * 1024 + b * 128 + p;
        segA8[si] = Aw;
        segB8[si] = Bw;
      }
      Aw = 1.f;
      Bw = 0.f;
    }
  }

  const size_t slot = (size_t)(b * 128 + p) * NCH + ch;
  *(float4*)(cbuf + slot * 128 + cl * 4) = make_float4(C[0], C[1], C[2], C[3]);
  *(float4*)(cbuf + slot * 128 + cl * 4 + 64) =
      make_float4(C[4], C[5], C[6], C[7]);
  if (cl == 0) {
    const size_t ci = (size_t)ch * 1024 + b * 128 + p;
    abuf[ci] = Af;
    nbufB[ci] = Bn;
  }
}

// ---------------------------------------------------------------------------
// hscan3 = ndenom + hscan2 fused (proven round 10). grid 512 (b, ch, qtr),
// block 512. Stages q/k (full 128h) + i,f (ALL 128 p) + v,o (own qtr).
// Den phase: thread (seg = tid>>7, p = tid&127) composes its n-prefix from
// register-unrolled chunk summaries (<=15) + 8-step summaries (<=3), replays
// 8 steps from LDS, then full-wave 6-step DPP reduce + cross-wave combine ->
// den[32]; o scaled in LDS; then round-7 replay verbatim. LDS 72.4 KB.
// ---------------------------------------------------------------------------
__global__ __launch_bounds__(512)
void hscan3_kernel(const float* __restrict__ act, float* __restrict__ hout,
                   const float* __restrict__ cbuf,
                   const float* __restrict__ abuf,
                   const float* __restrict__ nbufB,
                   const float* __restrict__ segA8,
                   const float* __restrict__ segB8) {
  __shared__ __align__(16) float qt[CL][128];    // 16 KB
  __shared__ __align__(16) float kt[CL][128];    // 16 KB
  __shared__ __align__(16) float iff[CL][256];   // 32 KB (i,f all 128 p)
  __shared__ __align__(16) float vot[CL][64];    // 8 KB (v,o own qtr)
  __shared__ float den_part[4][8][2];
  __shared__ float den[CL];
  const int tid = threadIdx.x;
  const int lane = tid & 63, wid = tid >> 6;
  const int blk = blockIdx.x;
  const int b = blk & 7, ch = (blk >> 3) & (NCH - 1), qtr = blk >> 7;
  const int t0 = ch * CL;
  const int p0 = qtr * 32;
  const size_t boff = (size_t)b * TT * HH;
  const float* qg = act + boff;
  const float* kg = act + BTH + boff;
  const float* ifg = act + 2 * BTH + 2 * boff;
  const float* vog = act + 4 * BTH + 2 * boff;

#pragma unroll
  for (int i = 0; i < CL / 16; ++i) {
    const int u = tid + 512 * i;
    const int r = u >> 5, c = (u & 31) * 4;
    *(float4*)&qt[r][c] = *(const float4*)(qg + (size_t)(t0 + r) * HH + c);
    *(float4*)&kt[r][c] = *(const float4*)(kg + (size_t)(t0 + r) * HH + c);
  }
#pragma unroll
  for (int i = 0; i < 4; ++i) {                  // CL x 256 = 2048 f4
    const int u = tid + 512 * i;
    const int r = u >> 6, c = (u & 63) * 4;
    *(float4*)&iff[r][c] =
        *(const float4*)(ifg + (size_t)(t0 + r) * 2 * HH + c);
  }
  {
    const int r = tid >> 4, c = (tid & 15) * 4;
    *(float4*)&vot[r][c] =
        *(const float4*)(vog + (size_t)(t0 + r) * 2 * HH + 2 * p0 + c);
  }
  __syncthreads();

  // ---- den phase: thread = (seg, pd) ----
  {
    const int seg = tid >> 7, pd = tid & 127;
    const size_t cidx = (size_t)b * 128 + pd;
    // register-unrolled summary loads (compile-time indices -> no scratch,
    // loads issue in parallel; compose chain is then pure FMA)
    float av[NCH], bv[NCH];
#pragma unroll
    for (int g = 0; g < NCH; ++g) {
      av[g] = abuf[(size_t)g * 1024 + cidx];
      bv[g] = nbufB[(size_t)g * 1024 + cidx];
    }
    float a8[3], b8[3];
#pragma unroll
    for (int s = 0; s < 3; ++s) {
      const size_t si = (size_t)(ch * 4 + s) * 1024 + cidx;
      a8[s] = segA8[si];
      b8[s] = segB8[si];
    }
    float n = 0.f;
#pragma unroll
    for (int g = 0; g < NCH; ++g)
      if (g < ch) n = fmaf(av[g], n, bv[g]);
#pragma unroll
    for (int s = 0; s < 3; ++s)
      if (s < seg) n = fmaf(a8[s], n, b8[s]);
    // 8 local steps from LDS; prod = OLD n * q (reference semantics)
    float prod[8];
#pragma unroll
    for (int j = 0; j < 8; ++j) {
      const int tl = seg * 8 + j;
      const float iv = iff[tl][2 * pd];
      const float fv = iff[tl][2 * pd + 1];
      prod[j] = n * qt[tl][pd];
      n = fmaf(fv, n, iv * kt[tl][pd]);
    }
    // full-wave reduce (64 p's per wave) -> lane 63
#pragma unroll
    for (int j = 0; j < 8; ++j) {
      float s = prod[j];
      s = dpp_add<0x111>(s);
      s = dpp_add<0x112>(s);
      s = dpp_add<0x114>(s);
      s = dpp_add<0x118>(s);
      s = dpp_add<0x142>(s);
      s = dpp_add<0x143>(s);
      prod[j] = s;
    }
    if (lane == 63) {
#pragma unroll
      for (int j = 0; j < 8; ++j) den_part[seg][j][wid & 1] = prod[j];
    }
  }
  __syncthreads();
  if (tid < CL) {
    const int s_ = tid >> 3, j_ = tid & 7;
    const float d = den_part[s_][j_][0] + den_part[s_][j_][1];
    den[tid] = __builtin_amdgcn_rcpf(fmaxf(fabsf(d), 1.0f));
  }
  __syncthreads();
  {
    int u = tid;                                 // 32 t x 32 pp o-elements
    vot[u >> 5][2 * (u & 31) + 1] *= den[u >> 5];
    u = tid + 512;
    vot[u >> 5][2 * (u & 31) + 1] *= den[u >> 5];
  }
  __syncthreads();

  // ---- replay (round-7 hscan2, gif from iff) ----
  const int pl = lane >> 4, cl = lane & 15;
  const int plocal = wid * 4 + pl;
  const int p = p0 + plocal;

  float C[8];
#pragma unroll
  for (int j = 0; j < 8; ++j) C[j] = 0.f;
  {
    const size_t cb = (size_t)(b * 128 + p) * NCH;
#pragma unroll 1
    for (int g = 0; g < ch; ++g) {
      const float a = abuf[(size_t)g * 1024 + b * 128 + p];
      const float4 b0 = *(const float4*)(cbuf + (cb + g) * 128 + cl * 4);
      const float4 b1 = *(const float4*)(cbuf + (cb + g) * 128 + cl * 4 + 64);
      C[0] = fmaf(a, C[0], b0.x);
      C[1] = fmaf(a, C[1], b0.y);
      C[2] = fmaf(a, C[2], b0.z);
      C[3] = fmaf(a, C[3], b0.w);
      C[4] = fmaf(a, C[4], b1.x);
      C[5] = fmaf(a, C[5], b1.y);
      C[6] = fmaf(a, C[6], b1.z);
      C[7] = fmaf(a, C[7], b1.w);
    }
  }
  float* hbase = hout + boff + p;

#pragma unroll 4
  for (int t = 0; t < CL; ++t) {
    const float2 gif = *(const float2*)&iff[t][2 * p];
    const float2 gvo = *(const float2*)&vot[t][2 * plocal];
    const float4 q0 = *(const float4*)&qt[t][cl * 4];
    const float4 q1 = *(const float4*)&qt[t][cl * 4 + 64];
    const float4 k0 = *(const float4*)&kt[t][cl * 4];
    const float4 k1 = *(const float4*)&kt[t][cl * 4 + 64];
    // h-tilde partial from OLD C
    float s0 = C[0] * q0.x;
    float s1 = C[4] * q1.x;
    s0 = fmaf(C[1], q0.y, s0);
    s1 = fmaf(C[5], q1.y, s1);
    s0 = fmaf(C[2], q0.z, s0);
    s1 = fmaf(C[6], q1.z, s1);
    s0 = fmaf(C[3], q0.w, s0);
    s1 = fmaf(C[7], q1.w, s1);
    float s = s0 + s1;
    // C update
    const float a = gif.x * gvo.x;               // i*v
    const float f = gif.y;
    C[0] = fmaf(f, C[0], a * k0.x);
    C[1] = fmaf(f, C[1], a * k0.y);
    C[2] = fmaf(f, C[2], a * k0.z);
    C[3] = fmaf(f, C[3], a * k0.w);
    C[4] = fmaf(f, C[4], a * k1.x);
    C[5] = fmaf(f, C[5], a * k1.y);
    C[6] = fmaf(f, C[6], a * k1.z);
    C[7] = fmaf(f, C[7], a * k1.w);
    // reduce over the 16-lane row: lane cl==15 holds the full col-sum
    s = dpp_add<0x111>(s);
    s = dpp_add<0x112>(s);
    s = dpp_add<0x114>(s);
    s = dpp_add<0x118>(s);
    if (cl == 15) hbase[(size_t)(t0 + t) * HH] = s * gvo.y;  // o*invden
  }
}

// ---------------------------------------------------------------------------
extern "C" void kernel_launch(void* const* d_in, const int* in_sizes, int n_in,
                              void* d_out, int out_size, void* d_ws,
                              size_t ws_size, hipStream_t stream) {
  (void)in_sizes; (void)n_in; (void)out_size; (void)ws_size;
  const float* x = (const float*)d_in[0];
  float* act = (float*)d_ws;                     // 6 * BTH floats
  float* hbuf = act + 6 * BTH;                   // BTH floats (layer-1 h)
  float* cbuf = act + 7 * BTH;                   // 1024*NCH*128 floats (8 MB)
  float* abuf = cbuf + (size_t)1024 * NCH * 128; // 16K floats
  float* nbufB = abuf + 16384;                   // 16K floats
  float* segA8 = nbufB + 16384;                  // 64K floats
  float* segB8 = segA8 + 65536;                  // 64K floats
  float* Wt = (float*)d_out;                     // [0, 196608)

  WArgs wa;
  for (int j = 0; j < 6; ++j) wa.W[j] = (const float*)d_in[1 + j];
  transpose_w<<<dim3(16, 12), 256, 0, stream>>>(wa, Wt);

  for (int l = 0; l < 2; ++l) {
    BArgs ba;
    for (int j = 0; j < 6; ++j)
      ba.b[j] = (const float*)d_in[7 + j] + (size_t)l * HH;
    const float* wtl = Wt + (size_t)l * 6 * HH * DD;
    const float* xin = (l == 0) ? x : hbuf;
    float* hdst = (l == 0) ? hbuf : (float*)d_out;
    proj_kernel<<<dim3(BT_ / 64, 6), 256, 0, stream>>>(xin, wtl, ba, act);
    cseg2_kernel<<<512, 512, 0, stream>>>(act, cbuf, abuf, nbufB, segA8,
                                          segB8);
    hscan3_kernel<<<512, 512, 0, stream>>>(act, hdst, cbuf, abuf, nbufB,
                                           segA8, segB8);
  }
}